// Round 6
// baseline (188.071 us; speedup 1.0000x reference)
//
#include <hip/hip_runtime.h>
#include <hip/hip_bf16.h>

#define D_MODEL 1024
#define NHEADS 16
#define HD 64
#define BATCH 2
#define SEQ 2048
#define BS (BATCH*SEQ)   // 4096

typedef __bf16 bf16;
typedef bf16 bf16x4 __attribute__((ext_vector_type(4)));
typedef bf16 bf16x8 __attribute__((ext_vector_type(8)));
typedef float f32x4 __attribute__((ext_vector_type(4)));

#define AS1 __attribute__((address_space(1)))
#define AS3 __attribute__((address_space(3)))

__device__ __forceinline__ void gload_lds16(const void* g, void* l) {
  __builtin_amdgcn_global_load_lds((AS1 const unsigned int*)g, (AS3 unsigned int*)l, 16, 0, 0);
}

// ---------------- elementwise f32 -> bf16 ----------------
__global__ void cvt_bf16(const float* __restrict__ in, bf16* __restrict__ out, int n8) {
  int i = blockIdx.x * blockDim.x + threadIdx.x;
  int stride = gridDim.x * blockDim.x;
  for (; i < n8; i += stride) {
    const float4* p = (const float4*)(in + (size_t)i * 8);
    float4 a = p[0], b = p[1];
    bf16x8 o;
    o[0]=(bf16)a.x; o[1]=(bf16)a.y; o[2]=(bf16)a.z; o[3]=(bf16)a.w;
    o[4]=(bf16)b.x; o[5]=(bf16)b.y; o[6]=(bf16)b.z; o[7]=(bf16)b.w;
    *(bf16x8*)(out + (size_t)i * 8) = o;
  }
}

// ---------------- transpose+convert: in f32 [R][C] -> out bf16 [C][R] ----------------
__global__ void transpose_cvt(const float* __restrict__ in, bf16* __restrict__ out, int R, int C) {
  __shared__ bf16 tile[64][72];
  const int t = threadIdx.x;
  const int r0 = blockIdx.x * 64;
  const int c0 = blockIdx.y * 64;
  {
    int r = t >> 2, cc = (t & 3) * 16;
    const float* src = in + (size_t)(r0 + r) * C + c0 + cc;
    #pragma unroll
    for (int j = 0; j < 16; j += 4) {
      float4 v = *(const float4*)(src + j);
      tile[r][cc + j + 0] = (bf16)v.x;
      tile[r][cc + j + 1] = (bf16)v.y;
      tile[r][cc + j + 2] = (bf16)v.z;
      tile[r][cc + j + 3] = (bf16)v.w;
    }
  }
  __syncthreads();
  {
    int c = t >> 2, rr = (t & 3) * 16;
    bf16* dst = out + (size_t)(c0 + c) * R + r0 + rr;
    bf16x8 o0, o1;
    #pragma unroll
    for (int j = 0; j < 8; j++) { o0[j] = tile[rr + j][c]; o1[j] = tile[rr + 8 + j][c]; }
    *(bf16x8*)dst = o0;
    *(bf16x8*)(dst + 8) = o1;
  }
}

// ---------------- V transpose: KV bf16 [BS][2*D] -> Vt bf16 [B][H][HD][SEQ] ----------------
__global__ void vtranspose(const bf16* __restrict__ KV, bf16* __restrict__ Vt) {
  __shared__ bf16 tile[64][72];
  const int t = threadIdx.x;
  const int s0 = blockIdx.x * 64;
  const int h = blockIdx.y;
  const int b = blockIdx.z;
  {
    int s = t >> 2, dc = (t & 3) * 16;
    const bf16* src = KV + (size_t)(b * SEQ + s0 + s) * (2 * D_MODEL) + h * 128 + 64 + dc;
    *(bf16x8*)&tile[s][dc] = *(const bf16x8*)src;
    *(bf16x8*)&tile[s][dc + 8] = *(const bf16x8*)(src + 8);
  }
  __syncthreads();
  {
    int d = t >> 2, sc = (t & 3) * 16;
    bf16* dst = Vt + ((size_t)((b * NHEADS + h) * HD + d)) * SEQ + s0 + sc;
    bf16x8 o0, o1;
    #pragma unroll
    for (int j = 0; j < 8; j++) { o0[j] = tile[sc + j][d]; o1[j] = tile[sc + 8 + j][d]; }
    *(bf16x8*)dst = o0;
    *(bf16x8*)(dst + 8) = o1;
  }
}

// ---------------- mask zero-scan ----------------
__global__ void mask_scan(const float* __restrict__ mask, int n4, int* __restrict__ flag) {
  int i = blockIdx.x * blockDim.x + threadIdx.x;
  int stride = gridDim.x * blockDim.x;
  int any = 0;
  for (; i < n4; i += stride) {
    float4 v = *(const float4*)(mask + (size_t)i * 4);
    if (v.x != 0.f || v.y != 0.f || v.z != 0.f || v.w != 0.f) any = 1;
  }
  if (__ballot(any) && (threadIdx.x & 63) == 0) atomicOr(flag, 1);
}

// ---------------- GEMM: C[M][N] = A[M][K] @ Bt[N][K]^T + bias ----------------
template <typename OutT>
__global__ __launch_bounds__(256)
void gemm_bt(const bf16* __restrict__ A, const bf16* __restrict__ Bt,
             const float* __restrict__ bias, OutT* __restrict__ C,
             int M, int N, int K) {
  __shared__ char lds[32768];
  char* Alds = lds;
  char* Blds = lds + 16384;
  const int t = threadIdx.x;
  const int lane = t & 63;
  const int wid = t >> 6;
  const int m0 = blockIdx.x * 128;
  const int n0 = blockIdx.y * 128;
  const int wr = wid >> 1, wc = wid & 1;

  f32x4 acc[4][4] = {};

  int rowL[4], colL[4];
  #pragma unroll
  for (int i = 0; i < 4; i++) {
    int L = t * 16 + i * 4096;
    int r = L >> 7;
    rowL[i] = r;
    colL[i] = (L & 127) ^ ((r & 7) << 4);
  }
  const char* Ab = (const char*)A;
  const char* Bb = (const char*)Bt;
  const size_t rs = (size_t)K * 2;

  for (int k0 = 0; k0 < K; k0 += 64) {
    #pragma unroll
    for (int i = 0; i < 4; i++) {
      gload_lds16(Ab + (size_t)(m0 + rowL[i]) * rs + (size_t)k0 * 2 + colL[i],
                  Alds + i * 4096 + t * 16);
      gload_lds16(Bb + (size_t)(n0 + rowL[i]) * rs + (size_t)k0 * 2 + colL[i],
                  Blds + i * 4096 + t * 16);
    }
    __syncthreads();
    #pragma unroll
    for (int kb = 0; kb < 2; kb++) {
      bf16x8 af[4], bfr[4];
      #pragma unroll
      for (int m = 0; m < 4; m++) {
        int r = wr * 64 + m * 16 + (lane & 15);
        int cb = (kb * 64 + ((lane >> 4) << 4)) ^ ((r & 7) << 4);
        af[m] = *(const bf16x8*)(Alds + r * 128 + cb);
      }
      #pragma unroll
      for (int n = 0; n < 4; n++) {
        int r = wc * 64 + n * 16 + (lane & 15);
        int cb = (kb * 64 + ((lane >> 4) << 4)) ^ ((r & 7) << 4);
        bfr[n] = *(const bf16x8*)(Blds + r * 128 + cb);
      }
      #pragma unroll
      for (int m = 0; m < 4; m++)
        #pragma unroll
        for (int n = 0; n < 4; n++)
          acc[m][n] = __builtin_amdgcn_mfma_f32_16x16x32_bf16(af[m], bfr[n], acc[m][n], 0, 0, 0);
    }
    __syncthreads();
  }

  #pragma unroll
  for (int m = 0; m < 4; m++) {
    const int rb = m0 + wr * 64 + m * 16 + ((lane >> 4) << 2);
    #pragma unroll
    for (int n = 0; n < 4; n++) {
      const int cg = n0 + wc * 64 + n * 16 + (lane & 15);
      const float bv = bias[cg];
      #pragma unroll
      for (int j = 0; j < 4; j++) {
        C[(size_t)(rb + j) * N + cg] = (OutT)(acc[m][n][j] + bv);
      }
    }
  }
}

// ---------------- flash attention (swapped QK^T, dbuf staging, 16q/wave) ------
// 4 waves x 16 q-rows = 64 q/block; grid = B*H*(SEQ/64) = 1024 blocks.
// LDS = 2x16KB K/V dbuf + 4x2KB P = 40KB -> 4 blocks/CU = 16 waves/CU.
// QK^T computed as mfma(K,Q): each lane holds P of ONE q row (q=lane&15)
// -> softmax reduce = in-lane tree + 2 shfl. exp via exp2f (compiler
// pipelines v_exp_f32). P written as 8B bf16x4 (4 writes/iter).
__global__ __launch_bounds__(256)
void attn_kernel(const bf16* __restrict__ Qb, const bf16* __restrict__ KV,
                 const bf16* __restrict__ Vt, const float* __restrict__ mask,
                 const int* __restrict__ flag, bf16* __restrict__ vals) {
  __shared__ char lds[40960];
  // buf c: K at c*16384, V at c*16384+8192; P per wave at 32768 + wid*2048
  const int t = threadIdx.x;
  const int lane = t & 63;
  const int wid = t >> 6;
  const int g = lane >> 4;          // 16-lane group 0..3
  const int lq = lane & 15;         // this lane's q within 16
  char* Pw = lds + 32768 + wid * 2048;   // [16 q][128B], XOR-swizzled rows

  // XCD-bijective swizzle: 1024 blocks, 8 XCDs, 128 consecutive logical wgs
  // per XCD (same b, 4 heads -> 2MB K+V fits 4MB L2).
  int wg = ((blockIdx.x & 7) << 7) | (blockIdx.x >> 3);
  const int qt = wg & 31;
  const int h = (wg >> 5) & 15;
  const int b = wg >> 9;
  const int q0 = qt * 64 + wid * 16;
  const bool use_mask = (*flag) != 0;

  const float SCL = 0.125f * 1.44269504f;   // 1/sqrt(64) * log2(e)

  // Q fragments (B-operand: rows = q)
  bf16x8 qf[2];
  #pragma unroll
  for (int kb = 0; kb < 2; kb++) {
    int r = q0 + lq;
    qf[kb] = *(const bf16x8*)(Qb + (size_t)(b * SEQ + r) * D_MODEL + h * HD + kb * 32 + g * 8);
  }

  f32x4 oacc[4] = {};
  float mrun = -1e30f, lrun = 0.f;

  int rowL[2], colL[2];
  #pragma unroll
  for (int i = 0; i < 2; i++) {
    int L = t * 16 + i * 4096;
    int r = L >> 7;
    rowL[i] = r;
    colL[i] = (L & 127) ^ ((r & 7) << 4);
  }
  const char* KVb = (const char*)KV;
  const char* Vtb = (const char*)Vt;

  // stage K/V tile kt into buffer c
  auto stage = [&](int kt, int c) {
    const int kv0 = kt * 64;
    char* Kb = lds + c * 16384;
    char* Vb = Kb + 8192;
    #pragma unroll
    for (int i = 0; i < 2; i++) {
      gload_lds16(KVb + (size_t)(b * SEQ + kv0 + rowL[i]) * (2 * D_MODEL * 2) + h * 256 + colL[i],
                  Kb + i * 4096 + t * 16);
      gload_lds16(Vtb + (size_t)((b * NHEADS + h) * HD + rowL[i]) * (SEQ * 2) + kv0 * 2 + colL[i],
                  Vb + i * 4096 + t * 16);
    }
  };

  stage(0, 0);
  __syncthreads();
  int cur = 0;

  const int NT = SEQ / 64;
  for (int kt = 0; kt < NT; kt++) {
    if (kt + 1 < NT) stage(kt + 1, cur ^ 1);   // prefetch overlaps compute
    char* Klds = lds + cur * 16384;
    char* Vlds = Klds + 8192;
    const int kv0 = kt * 64;

    // S^T = K Q^T : sacc[n] row = kv (n*16 + g*4 + j), col = q (lq)
    f32x4 sacc[4] = {};
    __builtin_amdgcn_s_setprio(1);
    #pragma unroll
    for (int kb = 0; kb < 2; kb++) {
      bf16x8 kf[4];
      #pragma unroll
      for (int n = 0; n < 4; n++) {
        int r = n * 16 + lq;
        int cb = (kb * 64 + (g << 4)) ^ ((r & 7) << 4);
        kf[n] = *(const bf16x8*)(Klds + r * 128 + cb);
      }
      #pragma unroll
      for (int n = 0; n < 4; n++)
        sacc[n] = __builtin_amdgcn_mfma_f32_16x16x32_bf16(kf[n], qf[kb], sacc[n], 0, 0, 0);
    }
    __builtin_amdgcn_s_setprio(0);

    // scale into exp2 domain + optional mask
    #pragma unroll
    for (int n = 0; n < 4; n++)
      #pragma unroll
      for (int j = 0; j < 4; j++)
        sacc[n][j] *= SCL;
    if (use_mask) {
      int qg = q0 + lq;
      const float* mrow = mask + ((size_t)b * SEQ + qg) * SEQ + kv0;
      #pragma unroll
      for (int n = 0; n < 4; n++)
        #pragma unroll
        for (int j = 0; j < 4; j++)
          sacc[n][j] += mrow[n * 16 + g * 4 + j] * 1.44269504f;
    }

    // row max for this lane's q: in-lane tree + 2 shfl (over g-groups)
    float a0 = fmaxf(fmaxf(sacc[0][0], sacc[0][1]), fmaxf(sacc[0][2], sacc[0][3]));
    float a1 = fmaxf(fmaxf(sacc[1][0], sacc[1][1]), fmaxf(sacc[1][2], sacc[1][3]));
    float a2 = fmaxf(fmaxf(sacc[2][0], sacc[2][1]), fmaxf(sacc[2][2], sacc[2][3]));
    float a3 = fmaxf(fmaxf(sacc[3][0], sacc[3][1]), fmaxf(sacc[3][2], sacc[3][3]));
    float pm = fmaxf(fmaxf(a0, a1), fmaxf(a2, a3));
    pm = fmaxf(pm, __shfl_xor(pm, 16, 64));
    pm = fmaxf(pm, __shfl_xor(pm, 32, 64));

    // defer-max: rescale only when some row's max grew (P stays <= 1)
    if (!__all(pm <= mrun)) {
      float mn = fmaxf(mrun, pm);
      float sf = exp2f(mrun - mn);
      mrun = mn;
      lrun *= sf;
      // oacc rows are q = g*4 + j; fetch that q's sf from lane g*4+j
      float sfj[4];
      #pragma unroll
      for (int j = 0; j < 4; j++) sfj[j] = __shfl(sf, (g << 2) + j, 64);
      #pragma unroll
      for (int n = 0; n < 4; n++)
        #pragma unroll
        for (int j = 0; j < 4; j++)
          oacc[n][j] *= sfj[j];
    }

    // P = exp2(S - m): one 8B bf16x4 write per n; row-sum via tree
    {
      char* prow = Pw + lq * 128;
      int swz = (lq & 7) << 4;
      float rsn[4];
      #pragma unroll
      for (int n = 0; n < 4; n++) {
        float e0 = exp2f(sacc[n][0] - mrun);
        float e1 = exp2f(sacc[n][1] - mrun);
        float e2 = exp2f(sacc[n][2] - mrun);
        float e3 = exp2f(sacc[n][3] - mrun);
        rsn[n] = (e0 + e1) + (e2 + e3);
        bf16x4 p = {(bf16)e0, (bf16)e1, (bf16)e2, (bf16)e3};
        *(bf16x4*)(prow + ((n * 32 + g * 8) ^ swz)) = p;
      }
      float rs = (rsn[0] + rsn[1]) + (rsn[2] + rsn[3]);
      rs += __shfl_xor(rs, 16, 64);
      rs += __shfl_xor(rs, 32, 64);
      lrun += rs;
    }

    // wave-private P: drain LDS writes before fragment reads
    asm volatile("s_waitcnt lgkmcnt(0)" ::: "memory");
    __builtin_amdgcn_sched_barrier(0);

    // O += P @ V   (A = P rows q, B = V^T rows d)
    __builtin_amdgcn_s_setprio(1);
    #pragma unroll
    for (int kb = 0; kb < 2; kb++) {
      bf16x8 pf, vf[4];
      {
        int cb = (kb * 64 + (g << 4)) ^ ((lq & 7) << 4);
        pf = *(const bf16x8*)(Pw + lq * 128 + cb);
      }
      #pragma unroll
      for (int n = 0; n < 4; n++) {
        int r = n * 16 + lq;
        int cb = (kb * 64 + (g << 4)) ^ ((r & 7) << 4);
        vf[n] = *(const bf16x8*)(Vlds + r * 128 + cb);
      }
      #pragma unroll
      for (int n = 0; n < 4; n++)
        oacc[n] = __builtin_amdgcn_mfma_f32_16x16x32_bf16(pf, vf[n], oacc[n], 0, 0, 0);
    }
    __builtin_amdgcn_s_setprio(0);

    __syncthreads();   // implicit vmcnt(0): prefetch landed; all reads of cur done
    cur ^= 1;
  }

  // normalize + write vals; oacc rows q = g*4+j -> lrun lives on lane g*4+j
  float inv[4];
  #pragma unroll
  for (int j = 0; j < 4; j++)
    inv[j] = 1.f / __shfl(lrun, (g << 2) + j, 64);
  #pragma unroll
  for (int n = 0; n < 4; n++) {
    int cg = h * HD + n * 16 + lq;
    #pragma unroll
    for (int j = 0; j < 4; j++) {
      int rg = b * SEQ + q0 + g * 4 + j;
      vals[(size_t)rg * D_MODEL + cg] = (bf16)(oacc[n][j] * inv[j]);
    }
  }
}

extern "C" void kernel_launch(void* const* d_in, const int* in_sizes, int n_in,
                              void* d_out, int out_size, void* d_ws, size_t ws_size,
                              hipStream_t stream) {
  const float* x    = (const float*)d_in[0];
  const float* y    = (const float*)d_in[1];
  const float* mask = (const float*)d_in[2];
  const float* Wkv  = (const float*)d_in[3];
  const float* bkv  = (const float*)d_in[4];
  const float* Wq   = (const float*)d_in[5];
  const float* bq   = (const float*)d_in[6];
  const float* Wo   = (const float*)d_in[7];
  const float* bo   = (const float*)d_in[8];
  float* out = (float*)d_out;

  char* ws = (char*)d_ws;
  bf16* xb   = (bf16*)(ws);                      // 8 MB
  bf16* yb   = (bf16*)(ws + (8ull << 20));       // 8 MB
  bf16* Wkvt = (bf16*)(ws + (16ull << 20));      // 4 MB
  bf16* Wqt  = (bf16*)(ws + (20ull << 20));      // 2 MB
  bf16* Wot  = (bf16*)(ws + (22ull << 20));      // 2 MB
  bf16* KVb  = (bf16*)(ws + (24ull << 20));      // 16 MB
  bf16* Qbuf = (bf16*)(ws + (40ull << 20));      // 8 MB
  bf16* Vt   = (bf16*)(ws + (48ull << 20));      // 8 MB
  bf16* vals = (bf16*)(ws + (56ull << 20));      // 8 MB
  int*  flag = (int*)(ws + (64ull << 20));       // 4 B

  hipMemsetAsync(flag, 0, 4, stream);
  mask_scan<<<2048, 256, 0, stream>>>(mask, BATCH * SEQ * SEQ / 4, flag);
  cvt_bf16<<<2048, 256, 0, stream>>>(x, xb, BS * D_MODEL / 8);
  cvt_bf16<<<2048, 256, 0, stream>>>(y, yb, BS * D_MODEL / 8);
  transpose_cvt<<<dim3(16, 32), 256, 0, stream>>>(Wkv, Wkvt, 1024, 2048);
  transpose_cvt<<<dim3(16, 16), 256, 0, stream>>>(Wq, Wqt, 1024, 1024);
  transpose_cvt<<<dim3(16, 16), 256, 0, stream>>>(Wo, Wot, 1024, 1024);
  gemm_bt<bf16><<<dim3(32, 16), 256, 0, stream>>>(xb, Wkvt, bkv, KVb, 4096, 2048, 1024);
  gemm_bt<bf16><<<dim3(32, 8), 256, 0, stream>>>(yb, Wqt, bq, Qbuf, 4096, 1024, 1024);
  vtranspose<<<dim3(32, 16, 2), 256, 0, stream>>>(KVb, Vt);
  attn_kernel<<<1024, 256, 0, stream>>>(Qbuf, KVb, Vt, mask, flag, vals);
  gemm_bt<float><<<dim3(32, 8), 256, 0, stream>>>(vals, Wot, bo, out, 4096, 1024, 1024);
}

// Round 9
// 187.622 us; speedup vs baseline: 1.0024x; 1.0024x over previous
//
#include <hip/hip_runtime.h>
#include <hip/hip_bf16.h>

#define D_MODEL 1024
#define NHEADS 16
#define HD 64
#define BATCH 2
#define SEQ 2048
#define BS (BATCH*SEQ)   // 4096

typedef __bf16 bf16;
typedef bf16 bf16x4 __attribute__((ext_vector_type(4)));
typedef bf16 bf16x8 __attribute__((ext_vector_type(8)));
typedef float f32x4 __attribute__((ext_vector_type(4)));

#define AS1 __attribute__((address_space(1)))
#define AS3 __attribute__((address_space(3)))

__device__ __forceinline__ void gload_lds16(const void* g, void* l) {
  __builtin_amdgcn_global_load_lds((AS1 const unsigned int*)g, (AS3 unsigned int*)l, 16, 0, 0);
}

// ---------------- elementwise f32 -> bf16 ----------------
__global__ void cvt_bf16(const float* __restrict__ in, bf16* __restrict__ out, int n8) {
  int i = blockIdx.x * blockDim.x + threadIdx.x;
  int stride = gridDim.x * blockDim.x;
  for (; i < n8; i += stride) {
    const float4* p = (const float4*)(in + (size_t)i * 8);
    float4 a = p[0], b = p[1];
    bf16x8 o;
    o[0]=(bf16)a.x; o[1]=(bf16)a.y; o[2]=(bf16)a.z; o[3]=(bf16)a.w;
    o[4]=(bf16)b.x; o[5]=(bf16)b.y; o[6]=(bf16)b.z; o[7]=(bf16)b.w;
    *(bf16x8*)(out + (size_t)i * 8) = o;
  }
}

// ---------------- transpose+convert: in f32 [R][C] -> out bf16 [C][R] ----------------
__global__ void transpose_cvt(const float* __restrict__ in, bf16* __restrict__ out, int R, int C) {
  __shared__ bf16 tile[64][72];
  const int t = threadIdx.x;
  const int r0 = blockIdx.x * 64;
  const int c0 = blockIdx.y * 64;
  {
    int r = t >> 2, cc = (t & 3) * 16;
    const float* src = in + (size_t)(r0 + r) * C + c0 + cc;
    #pragma unroll
    for (int j = 0; j < 16; j += 4) {
      float4 v = *(const float4*)(src + j);
      tile[r][cc + j + 0] = (bf16)v.x;
      tile[r][cc + j + 1] = (bf16)v.y;
      tile[r][cc + j + 2] = (bf16)v.z;
      tile[r][cc + j + 3] = (bf16)v.w;
    }
  }
  __syncthreads();
  {
    int c = t >> 2, rr = (t & 3) * 16;
    bf16* dst = out + (size_t)(c0 + c) * R + r0 + rr;
    bf16x8 o0, o1;
    #pragma unroll
    for (int j = 0; j < 8; j++) { o0[j] = tile[rr + j][c]; o1[j] = tile[rr + 8 + j][c]; }
    *(bf16x8*)dst = o0;
    *(bf16x8*)(dst + 8) = o1;
  }
}

// ---------------- mask zero-scan ----------------
__global__ void mask_scan(const float* __restrict__ mask, int n4, int* __restrict__ flag) {
  int i = blockIdx.x * blockDim.x + threadIdx.x;
  int stride = gridDim.x * blockDim.x;
  int any = 0;
  for (; i < n4; i += stride) {
    float4 v = *(const float4*)(mask + (size_t)i * 4);
    if (v.x != 0.f || v.y != 0.f || v.z != 0.f || v.w != 0.f) any = 1;
  }
  if (__ballot(any) && (threadIdx.x & 63) == 0) atomicOr(flag, 1);
}

// ---------------- GEMM: C[M][N] = A[M][K] @ Bt[N][K]^T + bias ----------------
// MODE 0: plain C write.
// MODE 1 (KV GEMM, N=2048): wc==0 waves (K half of each head) write C;
//   wc==1 waves (V half) write acc TRANSPOSED to Vt[B][H][HD][SEQ] and skip C.
template <typename OutT, int MODE>
__global__ __launch_bounds__(256)
void gemm_bt(const bf16* __restrict__ A, const bf16* __restrict__ Bt,
             const float* __restrict__ bias, OutT* __restrict__ C,
             bf16* __restrict__ Vt, int M, int N, int K) {
  __shared__ char lds[32768];
  char* Alds = lds;
  char* Blds = lds + 16384;
  const int t = threadIdx.x;
  const int lane = t & 63;
  const int wid = t >> 6;
  const int m0 = blockIdx.x * 128;
  const int n0 = blockIdx.y * 128;
  const int wr = wid >> 1, wc = wid & 1;

  f32x4 acc[4][4] = {};

  int rowL[4], colL[4];
  #pragma unroll
  for (int i = 0; i < 4; i++) {
    int L = t * 16 + i * 4096;
    int r = L >> 7;
    rowL[i] = r;
    colL[i] = (L & 127) ^ ((r & 7) << 4);
  }
  const char* Ab = (const char*)A;
  const char* Bb = (const char*)Bt;
  const size_t rs = (size_t)K * 2;

  for (int k0 = 0; k0 < K; k0 += 64) {
    #pragma unroll
    for (int i = 0; i < 4; i++) {
      gload_lds16(Ab + (size_t)(m0 + rowL[i]) * rs + (size_t)k0 * 2 + colL[i],
                  Alds + i * 4096 + t * 16);
      gload_lds16(Bb + (size_t)(n0 + rowL[i]) * rs + (size_t)k0 * 2 + colL[i],
                  Blds + i * 4096 + t * 16);
    }
    __syncthreads();
    #pragma unroll
    for (int kb = 0; kb < 2; kb++) {
      bf16x8 af[4], bfr[4];
      #pragma unroll
      for (int m = 0; m < 4; m++) {
        int r = wr * 64 + m * 16 + (lane & 15);
        int cb = (kb * 64 + ((lane >> 4) << 4)) ^ ((r & 7) << 4);
        af[m] = *(const bf16x8*)(Alds + r * 128 + cb);
      }
      #pragma unroll
      for (int n = 0; n < 4; n++) {
        int r = wc * 64 + n * 16 + (lane & 15);
        int cb = (kb * 64 + ((lane >> 4) << 4)) ^ ((r & 7) << 4);
        bfr[n] = *(const bf16x8*)(Blds + r * 128 + cb);
      }
      #pragma unroll
      for (int m = 0; m < 4; m++)
        #pragma unroll
        for (int n = 0; n < 4; n++)
          acc[m][n] = __builtin_amdgcn_mfma_f32_16x16x32_bf16(af[m], bfr[n], acc[m][n], 0, 0, 0);
    }
    __syncthreads();
  }

  if (MODE == 1 && wc == 1) {
    // V half: columns cg = n0+64+n*16+lq  ->  head h = n0>>7, d = n*16+lq.
    // Rows rb+j (j=0..3 consecutive) -> contiguous bf16x4 at Vt[d][s..s+3].
    const int h = n0 >> 7;
    const int bb = m0 >> 11;          // 128-row tiles never straddle batches
    #pragma unroll
    for (int n = 0; n < 4; n++) {
      const int d = n * 16 + (lane & 15);
      const int cg = n0 + 64 + d;
      const float bv = bias[cg];
      bf16* vrow = Vt + ((size_t)((bb * NHEADS + h) * HD + d)) * SEQ;
      #pragma unroll
      for (int m = 0; m < 4; m++) {
        const int rb = m0 + wr * 64 + m * 16 + ((lane >> 4) << 2);
        const int s = rb & (SEQ - 1);
        bf16x4 v;
        #pragma unroll
        for (int j = 0; j < 4; j++) v[j] = (bf16)(acc[m][n][j] + bv);
        *(bf16x4*)(vrow + s) = v;
      }
    }
  } else {
    #pragma unroll
    for (int m = 0; m < 4; m++) {
      const int rb = m0 + wr * 64 + m * 16 + ((lane >> 4) << 2);
      #pragma unroll
      for (int n = 0; n < 4; n++) {
        const int cg = n0 + wc * 64 + n * 16 + (lane & 15);
        const float bv = bias[cg];
        #pragma unroll
        for (int j = 0; j < 4; j++) {
          C[(size_t)(rb + j) * N + cg] = (OutT)(acc[m][n][j] + bv);
        }
      }
    }
  }
}

// ---------------- flash attention (swapped QK^T, dbuf staging, 32q/wave) ------
// 4 waves x 32 q-rows = 128 q/block; grid = B*H*(SEQ/128) = 512 blocks.
// QK^T computed as mfma(K,Q): each lane holds P of ONE q row (q=lane&15)
// -> softmax reduce = in-lane tree + 2 shfl. K/V double-buffered; prefetch
// issued before compute; one barrier per iteration. All LDS fragment
// offsets hoisted out of the loop. P written as bf16x4 (8B) stores.
__global__ __launch_bounds__(256)
void attn_kernel(const bf16* __restrict__ Qb, const bf16* __restrict__ KV,
                 const bf16* __restrict__ Vt, const float* __restrict__ mask,
                 const int* __restrict__ flag, bf16* __restrict__ vals) {
  __shared__ char lds[49152];
  // buf c: K at c*16384, V at c*16384+8192; P per wave at 32768 + wid*4096
  const int t = threadIdx.x;
  const int lane = t & 63;
  const int wid = t >> 6;
  const int g = lane >> 4;          // 16-lane group 0..3
  const int lq = lane & 15;         // this lane's q within 16
  char* Pw = lds + 32768 + wid * 4096;   // [32 q][128B], XOR-swizzled rows

  // XCD-bijective swizzle: 512 blocks, 8 XCDs, 64 consecutive logical wgs
  // per XCD (same b, 4 heads -> 2MB K+V fits 4MB L2).
  int wg = ((blockIdx.x & 7) << 6) | (blockIdx.x >> 3);
  const int qt = wg & 15;
  const int h = (wg >> 4) & 15;
  const int b = wg >> 8;
  const int q0 = qt * 128 + wid * 32;
  const bool use_mask = (*flag) != 0;

  const float SCL = 0.125f * 1.44269504f;   // 1/sqrt(64) * log2(e)

  // Q fragments (B-operand: rows = q)
  bf16x8 qf[2][2];
  #pragma unroll
  for (int m = 0; m < 2; m++)
    #pragma unroll
    for (int kb = 0; kb < 2; kb++) {
      int r = q0 + m * 16 + lq;
      qf[m][kb] = *(const bf16x8*)(Qb + (size_t)(b * SEQ + r) * D_MODEL + h * HD + kb * 32 + g * 8);
    }

  f32x4 oacc[2][4] = {};
  float mrun[2], lrun[2];
  mrun[0] = mrun[1] = -1e30f;
  lrun[0] = lrun[1] = 0.f;

  // hoisted LDS byte offsets (loop-invariant)
  int kvOff[2][4];   // K and V fragment offsets (same formula)
  #pragma unroll
  for (int kb = 0; kb < 2; kb++)
    #pragma unroll
    for (int n = 0; n < 4; n++) {
      int r = n * 16 + lq;
      kvOff[kb][n] = r * 128 + ((kb * 64 + (g << 4)) ^ ((r & 7) << 4));
    }
  int pROff[2][2];   // P read offsets per (m, kb)
  #pragma unroll
  for (int m = 0; m < 2; m++)
    #pragma unroll
    for (int kb = 0; kb < 2; kb++) {
      int r = m * 16 + lq;
      pROff[m][kb] = r * 128 + ((kb * 64 + (g << 4)) ^ ((r & 7) << 4));
    }
  int pWOff[2][4];   // P write offsets per (m, n)
  #pragma unroll
  for (int m = 0; m < 2; m++) {
    int r = m * 16 + lq;
    int swz = (r & 7) << 4;
    #pragma unroll
    for (int n = 0; n < 4; n++)
      pWOff[m][n] = r * 128 + ((n * 32 + g * 8) ^ swz);
  }

  int rowL[2], colL[2];
  #pragma unroll
  for (int i = 0; i < 2; i++) {
    int L = t * 16 + i * 4096;
    int r = L >> 7;
    rowL[i] = r;
    colL[i] = (L & 127) ^ ((r & 7) << 4);
  }
  const char* KVb = (const char*)KV;
  const char* Vtb = (const char*)Vt;

  // stage K/V tile kt into buffer c
  auto stage = [&](int kt, int c) {
    const int kv0 = kt * 64;
    char* Kb = lds + c * 16384;
    char* Vb = Kb + 8192;
    #pragma unroll
    for (int i = 0; i < 2; i++) {
      gload_lds16(KVb + (size_t)(b * SEQ + kv0 + rowL[i]) * (2 * D_MODEL * 2) + h * 256 + colL[i],
                  Kb + i * 4096 + t * 16);
      gload_lds16(Vtb + (size_t)((b * NHEADS + h) * HD + rowL[i]) * (SEQ * 2) + kv0 * 2 + colL[i],
                  Vb + i * 4096 + t * 16);
    }
  };

  stage(0, 0);
  __syncthreads();
  int cur = 0;

  const int NT = SEQ / 64;
  for (int kt = 0; kt < NT; kt++) {
    if (kt + 1 < NT) stage(kt + 1, cur ^ 1);   // prefetch overlaps compute
    char* Klds = lds + cur * 16384;
    char* Vlds = Klds + 8192;
    const int kv0 = kt * 64;

    // S^T = K Q^T : sacc[m][n] row = kv (n*16+g*4+j), col = q (lq)
    f32x4 sacc[2][4] = {};
    __builtin_amdgcn_s_setprio(1);
    #pragma unroll
    for (int kb = 0; kb < 2; kb++) {
      bf16x8 kf[4];
      #pragma unroll
      for (int n = 0; n < 4; n++)
        kf[n] = *(const bf16x8*)(Klds + kvOff[kb][n]);
      #pragma unroll
      for (int m = 0; m < 2; m++)
        #pragma unroll
        for (int n = 0; n < 4; n++)
          sacc[m][n] = __builtin_amdgcn_mfma_f32_16x16x32_bf16(kf[n], qf[m][kb], sacc[m][n], 0, 0, 0);
    }
    __builtin_amdgcn_s_setprio(0);

    // scale into exp2 domain + optional mask
    #pragma unroll
    for (int m = 0; m < 2; m++)
      #pragma unroll
      for (int n = 0; n < 4; n++)
        #pragma unroll
        for (int j = 0; j < 4; j++)
          sacc[m][n][j] *= SCL;
    if (use_mask) {
      #pragma unroll
      for (int m = 0; m < 2; m++) {
        int qg = q0 + m * 16 + lq;
        const float* mrow = mask + ((size_t)b * SEQ + qg) * SEQ + kv0;
        #pragma unroll
        for (int n = 0; n < 4; n++)
          #pragma unroll
          for (int j = 0; j < 4; j++)
            sacc[m][n][j] += mrow[n * 16 + g * 4 + j] * 1.44269504f;
      }
    }

    // row max for this lane's q: in-lane tree + 2 shfl (over g-groups)
    float pm[2];
    #pragma unroll
    for (int m = 0; m < 2; m++) {
      float a0 = fmaxf(fmaxf(sacc[m][0][0], sacc[m][0][1]), fmaxf(sacc[m][0][2], sacc[m][0][3]));
      float a1 = fmaxf(fmaxf(sacc[m][1][0], sacc[m][1][1]), fmaxf(sacc[m][1][2], sacc[m][1][3]));
      float a2 = fmaxf(fmaxf(sacc[m][2][0], sacc[m][2][1]), fmaxf(sacc[m][2][2], sacc[m][2][3]));
      float a3 = fmaxf(fmaxf(sacc[m][3][0], sacc[m][3][1]), fmaxf(sacc[m][3][2], sacc[m][3][3]));
      float v = fmaxf(fmaxf(a0, a1), fmaxf(a2, a3));
      v = fmaxf(v, __shfl_xor(v, 16, 64));
      v = fmaxf(v, __shfl_xor(v, 32, 64));
      pm[m] = v;
    }

    // defer-max: rescale only when some row's max grew (P stays <= 1)
    int nogrow = (pm[0] <= mrun[0]) && (pm[1] <= mrun[1]);
    if (!__all(nogrow)) {
      #pragma unroll
      for (int m = 0; m < 2; m++) {
        float mn = fmaxf(mrun[m], pm[m]);
        float sf = exp2f(mrun[m] - mn);
        mrun[m] = mn;
        lrun[m] *= sf;
        // oacc rows are q = m*16 + g*4 + j; fetch that q's sf from lane g*4+j
        float sfj[4];
        #pragma unroll
        for (int j = 0; j < 4; j++) sfj[j] = __shfl(sf, (g << 2) + j, 64);
        #pragma unroll
        for (int n = 0; n < 4; n++)
          #pragma unroll
          for (int j = 0; j < 4; j++)
            oacc[m][n][j] *= sfj[j];
      }
    }

    // P = exp2(S - m): one 8B bf16x4 write per (m,n); row-sum via tree
    #pragma unroll
    for (int m = 0; m < 2; m++) {
      float rsn[4];
      #pragma unroll
      for (int n = 0; n < 4; n++) {
        float e0 = exp2f(sacc[m][n][0] - mrun[m]);
        float e1 = exp2f(sacc[m][n][1] - mrun[m]);
        float e2 = exp2f(sacc[m][n][2] - mrun[m]);
        float e3 = exp2f(sacc[m][n][3] - mrun[m]);
        rsn[n] = (e0 + e1) + (e2 + e3);
        bf16x4 p = {(bf16)e0, (bf16)e1, (bf16)e2, (bf16)e3};
        *(bf16x4*)(Pw + pWOff[m][n]) = p;
      }
      float rs = (rsn[0] + rsn[1]) + (rsn[2] + rsn[3]);
      rs += __shfl_xor(rs, 16, 64);
      rs += __shfl_xor(rs, 32, 64);
      lrun[m] += rs;
    }

    // wave-private P: drain LDS writes before fragment reads
    asm volatile("s_waitcnt lgkmcnt(0)" ::: "memory");
    __builtin_amdgcn_sched_barrier(0);

    // O += P @ V   (A = P rows q, B = V^T rows d)
    __builtin_amdgcn_s_setprio(1);
    #pragma unroll
    for (int kb = 0; kb < 2; kb++) {
      bf16x8 pf[2], vf[4];
      #pragma unroll
      for (int m = 0; m < 2; m++)
        pf[m] = *(const bf16x8*)(Pw + pROff[m][kb]);
      #pragma unroll
      for (int n = 0; n < 4; n++)
        vf[n] = *(const bf16x8*)(Vlds + kvOff[kb][n]);
      #pragma unroll
      for (int m = 0; m < 2; m++)
        #pragma unroll
        for (int n = 0; n < 4; n++)
          oacc[m][n] = __builtin_amdgcn_mfma_f32_16x16x32_bf16(pf[m], vf[n], oacc[m][n], 0, 0, 0);
    }
    __builtin_amdgcn_s_setprio(0);

    __syncthreads();   // implicit vmcnt(0): prefetch landed; all reads of cur done
    cur ^= 1;
  }

  // normalize + write vals; oacc rows q = m*16+g*4+j -> lrun lives on lane g*4+j
  #pragma unroll
  for (int m = 0; m < 2; m++) {
    float inv[4];
    #pragma unroll
    for (int j = 0; j < 4; j++)
      inv[j] = 1.f / __shfl(lrun[m], (g << 2) + j, 64);
    #pragma unroll
    for (int n = 0; n < 4; n++) {
      int cg = h * HD + n * 16 + lq;
      #pragma unroll
      for (int j = 0; j < 4; j++) {
        int rg = b * SEQ + q0 + m * 16 + g * 4 + j;
        vals[(size_t)rg * D_MODEL + cg] = (bf16)(oacc[m][n][j] * inv[j]);
      }
    }
  }
}

extern "C" void kernel_launch(void* const* d_in, const int* in_sizes, int n_in,
                              void* d_out, int out_size, void* d_ws, size_t ws_size,
                              hipStream_t stream) {
  const float* x    = (const float*)d_in[0];
  const float* y    = (const float*)d_in[1];
  const float* mask = (const float*)d_in[2];
  const float* Wkv  = (const float*)d_in[3];
  const float* bkv  = (const float*)d_in[4];
  const float* Wq   = (const float*)d_in[5];
  const float* bq   = (const float*)d_in[6];
  const float* Wo   = (const float*)d_in[7];
  const float* bo   = (const float*)d_in[8];
  float* out = (float*)d_out;

  char* ws = (char*)d_ws;
  bf16* xb   = (bf16*)(ws);                      // 8 MB
  bf16* yb   = (bf16*)(ws + (8ull << 20));       // 8 MB
  bf16* Wkvt = (bf16*)(ws + (16ull << 20));      // 4 MB
  bf16* Wqt  = (bf16*)(ws + (20ull << 20));      // 2 MB
  bf16* Wot  = (bf16*)(ws + (22ull << 20));      // 2 MB
  bf16* KVb  = (bf16*)(ws + (24ull << 20));      // 16 MB (V half unused)
  bf16* Qbuf = (bf16*)(ws + (40ull << 20));      // 8 MB
  bf16* Vt   = (bf16*)(ws + (48ull << 20));      // 8 MB
  bf16* vals = (bf16*)(ws + (56ull << 20));      // 8 MB
  int*  flag = (int*)(ws + (64ull << 20));       // 4 B

  hipMemsetAsync(flag, 0, 4, stream);
  mask_scan<<<2048, 256, 0, stream>>>(mask, BATCH * SEQ * SEQ / 4, flag);
  cvt_bf16<<<2048, 256, 0, stream>>>(x, xb, BS * D_MODEL / 8);
  cvt_bf16<<<2048, 256, 0, stream>>>(y, yb, BS * D_MODEL / 8);
  transpose_cvt<<<dim3(16, 32), 256, 0, stream>>>(Wkv, Wkvt, 1024, 2048);
  transpose_cvt<<<dim3(16, 16), 256, 0, stream>>>(Wq, Wqt, 1024, 1024);
  transpose_cvt<<<dim3(16, 16), 256, 0, stream>>>(Wo, Wot, 1024, 1024);
  // KV GEMM: K half -> KVb, V half -> Vt (transposed in epilogue)
  gemm_bt<bf16, 1><<<dim3(32, 16), 256, 0, stream>>>(xb, Wkvt, bkv, KVb, Vt, 4096, 2048, 1024);
  gemm_bt<bf16, 0><<<dim3(32, 8), 256, 0, stream>>>(yb, Wqt, bq, Qbuf, nullptr, 4096, 1024, 1024);
  attn_kernel<<<512, 256, 0, stream>>>(Qbuf, KVb, Vt, mask, flag, vals);
  gemm_bt<float, 0><<<dim3(32, 8), 256, 0, stream>>>(vals, Wot, bo, out, nullptr, 4096, 1024, 1024);
}

// Round 10
// 170.761 us; speedup vs baseline: 1.1014x; 1.0987x over previous
//
#include <hip/hip_runtime.h>
#include <hip/hip_bf16.h>

#define D_MODEL 1024
#define NHEADS 16
#define HD 64
#define BATCH 2
#define SEQ 2048
#define BS (BATCH*SEQ)   // 4096

typedef __bf16 bf16;
typedef bf16 bf16x4 __attribute__((ext_vector_type(4)));
typedef bf16 bf16x8 __attribute__((ext_vector_type(8)));
typedef float f32x4 __attribute__((ext_vector_type(4)));

#define AS1 __attribute__((address_space(1)))
#define AS3 __attribute__((address_space(3)))

__device__ __forceinline__ void gload_lds16(const void* g, void* l) {
  __builtin_amdgcn_global_load_lds((AS1 const unsigned int*)g, (AS3 unsigned int*)l, 16, 0, 0);
}

// 2^x as a single v_exp_f32 (+ s_nop for the trans-op read hazard).
// NON-volatile: pure value -> compiler may schedule/interleave freely.
__device__ __forceinline__ float exp2_fast(float x) {
  float r;
  asm("v_exp_f32 %0, %1\n\ts_nop 1" : "=v"(r) : "v"(x));
  return r;
}

// ---------------- elementwise f32 -> bf16 ----------------
__global__ void cvt_bf16(const float* __restrict__ in, bf16* __restrict__ out, int n8) {
  int i = blockIdx.x * blockDim.x + threadIdx.x;
  int stride = gridDim.x * blockDim.x;
  for (; i < n8; i += stride) {
    const float4* p = (const float4*)(in + (size_t)i * 8);
    float4 a = p[0], b = p[1];
    bf16x8 o;
    o[0]=(bf16)a.x; o[1]=(bf16)a.y; o[2]=(bf16)a.z; o[3]=(bf16)a.w;
    o[4]=(bf16)b.x; o[5]=(bf16)b.y; o[6]=(bf16)b.z; o[7]=(bf16)b.w;
    *(bf16x8*)(out + (size_t)i * 8) = o;
  }
}

// ---------------- transpose+convert: in f32 [R][C] -> out bf16 [C][R] ----------------
__global__ void transpose_cvt(const float* __restrict__ in, bf16* __restrict__ out, int R, int C) {
  __shared__ bf16 tile[64][72];
  const int t = threadIdx.x;
  const int r0 = blockIdx.x * 64;
  const int c0 = blockIdx.y * 64;
  {
    int r = t >> 2, cc = (t & 3) * 16;
    const float* src = in + (size_t)(r0 + r) * C + c0 + cc;
    #pragma unroll
    for (int j = 0; j < 16; j += 4) {
      float4 v = *(const float4*)(src + j);
      tile[r][cc + j + 0] = (bf16)v.x;
      tile[r][cc + j + 1] = (bf16)v.y;
      tile[r][cc + j + 2] = (bf16)v.z;
      tile[r][cc + j + 3] = (bf16)v.w;
    }
  }
  __syncthreads();
  {
    int c = t >> 2, rr = (t & 3) * 16;
    bf16* dst = out + (size_t)(c0 + c) * R + r0 + rr;
    bf16x8 o0, o1;
    #pragma unroll
    for (int j = 0; j < 8; j++) { o0[j] = tile[rr + j][c]; o1[j] = tile[rr + 8 + j][c]; }
    *(bf16x8*)dst = o0;
    *(bf16x8*)(dst + 8) = o1;
  }
}

// ---------------- mask zero-scan ----------------
__global__ void mask_scan(const float* __restrict__ mask, int n4, int* __restrict__ flag) {
  int i = blockIdx.x * blockDim.x + threadIdx.x;
  int stride = gridDim.x * blockDim.x;
  int any = 0;
  for (; i < n4; i += stride) {
    float4 v = *(const float4*)(mask + (size_t)i * 4);
    if (v.x != 0.f || v.y != 0.f || v.z != 0.f || v.w != 0.f) any = 1;
  }
  if (__ballot(any) && (threadIdx.x & 63) == 0) atomicOr(flag, 1);
}

// ---------------- GEMM: C[M][N] = (A[M][K] @ Bt[N][K]^T + bias) * scale ------
// MODE 0: plain C write.
// MODE 1 (KV GEMM, N=2048): wc==0 waves (K half of each head) write C;
//   wc==1 waves (V half) write acc TRANSPOSED to Vt[B][H][HD][SEQ] and skip C.
template <typename OutT, int MODE>
__global__ __launch_bounds__(256)
void gemm_bt(const bf16* __restrict__ A, const bf16* __restrict__ Bt,
             const float* __restrict__ bias, OutT* __restrict__ C,
             bf16* __restrict__ Vt, int M, int N, int K, float scale) {
  __shared__ char lds[32768];
  char* Alds = lds;
  char* Blds = lds + 16384;
  const int t = threadIdx.x;
  const int lane = t & 63;
  const int wid = t >> 6;
  const int m0 = blockIdx.x * 128;
  const int n0 = blockIdx.y * 128;
  const int wr = wid >> 1, wc = wid & 1;

  f32x4 acc[4][4] = {};

  int rowL[4], colL[4];
  #pragma unroll
  for (int i = 0; i < 4; i++) {
    int L = t * 16 + i * 4096;
    int r = L >> 7;
    rowL[i] = r;
    colL[i] = (L & 127) ^ ((r & 7) << 4);
  }
  const char* Ab = (const char*)A;
  const char* Bb = (const char*)Bt;
  const size_t rs = (size_t)K * 2;

  for (int k0 = 0; k0 < K; k0 += 64) {
    #pragma unroll
    for (int i = 0; i < 4; i++) {
      gload_lds16(Ab + (size_t)(m0 + rowL[i]) * rs + (size_t)k0 * 2 + colL[i],
                  Alds + i * 4096 + t * 16);
      gload_lds16(Bb + (size_t)(n0 + rowL[i]) * rs + (size_t)k0 * 2 + colL[i],
                  Blds + i * 4096 + t * 16);
    }
    __syncthreads();
    #pragma unroll
    for (int kb = 0; kb < 2; kb++) {
      bf16x8 af[4], bfr[4];
      #pragma unroll
      for (int m = 0; m < 4; m++) {
        int r = wr * 64 + m * 16 + (lane & 15);
        int cb = (kb * 64 + ((lane >> 4) << 4)) ^ ((r & 7) << 4);
        af[m] = *(const bf16x8*)(Alds + r * 128 + cb);
      }
      #pragma unroll
      for (int n = 0; n < 4; n++) {
        int r = wc * 64 + n * 16 + (lane & 15);
        int cb = (kb * 64 + ((lane >> 4) << 4)) ^ ((r & 7) << 4);
        bfr[n] = *(const bf16x8*)(Blds + r * 128 + cb);
      }
      #pragma unroll
      for (int m = 0; m < 4; m++)
        #pragma unroll
        for (int n = 0; n < 4; n++)
          acc[m][n] = __builtin_amdgcn_mfma_f32_16x16x32_bf16(af[m], bfr[n], acc[m][n], 0, 0, 0);
    }
    __syncthreads();
  }

  if (MODE == 1 && wc == 1) {
    // V half: columns cg = n0+64+n*16+lq  ->  head h = n0>>7, d = n*16+lq.
    // Rows rb+j (j=0..3 consecutive) -> contiguous bf16x4 at Vt[d][s..s+3].
    const int h = n0 >> 7;
    const int bb = m0 >> 11;          // 128-row tiles never straddle batches
    #pragma unroll
    for (int n = 0; n < 4; n++) {
      const int d = n * 16 + (lane & 15);
      const int cg = n0 + 64 + d;
      const float bv = bias[cg];
      bf16* vrow = Vt + ((size_t)((bb * NHEADS + h) * HD + d)) * SEQ;
      #pragma unroll
      for (int m = 0; m < 4; m++) {
        const int rb = m0 + wr * 64 + m * 16 + ((lane >> 4) << 2);
        const int s = rb & (SEQ - 1);
        bf16x4 v;
        #pragma unroll
        for (int j = 0; j < 4; j++) v[j] = (bf16)((acc[m][n][j] + bv) * scale);
        *(bf16x4*)(vrow + s) = v;
      }
    }
  } else {
    #pragma unroll
    for (int m = 0; m < 4; m++) {
      const int rb = m0 + wr * 64 + m * 16 + ((lane >> 4) << 2);
      #pragma unroll
      for (int n = 0; n < 4; n++) {
        const int cg = n0 + wc * 64 + n * 16 + (lane & 15);
        const float bv = bias[cg];
        #pragma unroll
        for (int j = 0; j < 4; j++) {
          C[(size_t)(rb + j) * N + cg] = (OutT)((acc[m][n][j] + bv) * scale);
        }
      }
    }
  }
}

// ---------------- flash attention (swapped QK^T, dbuf staging, 32q/wave) ------
// 4 waves x 32 q-rows = 128 q/block; grid = B*H*(SEQ/128) = 512 blocks.
// Q is PRE-SCALED by 0.125*log2(e) in its GEMM epilogue -> QK^T lands in the
// exp2 domain directly (no per-element scale here). mfma(K,Q): each lane
// holds P of ONE q row (q=lane&15) -> softmax reduce = in-lane tree + 2 shfl.
// exp = single v_exp_f32. K/V double-buffered; one barrier/iteration.
__global__ __launch_bounds__(256)
void attn_kernel(const bf16* __restrict__ Qb, const bf16* __restrict__ KV,
                 const bf16* __restrict__ Vt, const float* __restrict__ mask,
                 const int* __restrict__ flag, bf16* __restrict__ vals) {
  __shared__ char lds[49152];
  // buf c: K at c*16384, V at c*16384+8192; P per wave at 32768 + wid*4096
  const int t = threadIdx.x;
  const int lane = t & 63;
  const int wid = t >> 6;
  const int g = lane >> 4;          // 16-lane group 0..3
  const int lq = lane & 15;         // this lane's q within 16
  char* Pw = lds + 32768 + wid * 4096;   // [32 q][128B], XOR-swizzled rows

  // XCD-bijective swizzle: 512 blocks, 8 XCDs, 64 consecutive logical wgs
  // per XCD (same b, 4 heads -> 2MB K+V fits 4MB L2).
  int wg = ((blockIdx.x & 7) << 6) | (blockIdx.x >> 3);
  const int qt = wg & 15;
  const int h = (wg >> 4) & 15;
  const int b = wg >> 8;
  const int q0 = qt * 128 + wid * 32;
  const bool use_mask = (*flag) != 0;

  // Q fragments (B-operand: rows = q)
  bf16x8 qf[2][2];
  #pragma unroll
  for (int m = 0; m < 2; m++)
    #pragma unroll
    for (int kb = 0; kb < 2; kb++) {
      int r = q0 + m * 16 + lq;
      qf[m][kb] = *(const bf16x8*)(Qb + (size_t)(b * SEQ + r) * D_MODEL + h * HD + kb * 32 + g * 8);
    }

  f32x4 oacc[2][4] = {};
  float mrun[2], lrun[2];
  mrun[0] = mrun[1] = -1e30f;
  lrun[0] = lrun[1] = 0.f;

  // hoisted LDS byte offsets (loop-invariant)
  int kvOff[2][4];   // K and V fragment offsets (same formula)
  #pragma unroll
  for (int kb = 0; kb < 2; kb++)
    #pragma unroll
    for (int n = 0; n < 4; n++) {
      int r = n * 16 + lq;
      kvOff[kb][n] = r * 128 + ((kb * 64 + (g << 4)) ^ ((r & 7) << 4));
    }
  int pROff[2][2];   // P read offsets per (m, kb)
  #pragma unroll
  for (int m = 0; m < 2; m++)
    #pragma unroll
    for (int kb = 0; kb < 2; kb++) {
      int r = m * 16 + lq;
      pROff[m][kb] = r * 128 + ((kb * 64 + (g << 4)) ^ ((r & 7) << 4));
    }
  int pWOff[2][4];   // P write offsets per (m, n)
  #pragma unroll
  for (int m = 0; m < 2; m++) {
    int r = m * 16 + lq;
    int swz = (r & 7) << 4;
    #pragma unroll
    for (int n = 0; n < 4; n++)
      pWOff[m][n] = r * 128 + ((n * 32 + g * 8) ^ swz);
  }

  int rowL[2], colL[2];
  #pragma unroll
  for (int i = 0; i < 2; i++) {
    int L = t * 16 + i * 4096;
    int r = L >> 7;
    rowL[i] = r;
    colL[i] = (L & 127) ^ ((r & 7) << 4);
  }
  const char* KVb = (const char*)KV;
  const char* Vtb = (const char*)Vt;

  // stage K/V tile kt into buffer c
  auto stage = [&](int kt, int c) {
    const int kv0 = kt * 64;
    char* Kb = lds + c * 16384;
    char* Vb = Kb + 8192;
    #pragma unroll
    for (int i = 0; i < 2; i++) {
      gload_lds16(KVb + (size_t)(b * SEQ + kv0 + rowL[i]) * (2 * D_MODEL * 2) + h * 256 + colL[i],
                  Kb + i * 4096 + t * 16);
      gload_lds16(Vtb + (size_t)((b * NHEADS + h) * HD + rowL[i]) * (SEQ * 2) + kv0 * 2 + colL[i],
                  Vb + i * 4096 + t * 16);
    }
  };

  stage(0, 0);
  __syncthreads();
  int cur = 0;

  const int NT = SEQ / 64;
  for (int kt = 0; kt < NT; kt++) {
    if (kt + 1 < NT) stage(kt + 1, cur ^ 1);   // prefetch overlaps compute
    char* Klds = lds + cur * 16384;
    char* Vlds = Klds + 8192;
    const int kv0 = kt * 64;

    // S^T = K Q^T (already exp2-domain): sacc[m][n] row = kv, col = q (lq)
    f32x4 sacc[2][4] = {};
    __builtin_amdgcn_s_setprio(1);
    #pragma unroll
    for (int kb = 0; kb < 2; kb++) {
      bf16x8 kf[4];
      #pragma unroll
      for (int n = 0; n < 4; n++)
        kf[n] = *(const bf16x8*)(Klds + kvOff[kb][n]);
      #pragma unroll
      for (int m = 0; m < 2; m++)
        #pragma unroll
        for (int n = 0; n < 4; n++)
          sacc[m][n] = __builtin_amdgcn_mfma_f32_16x16x32_bf16(kf[n], qf[m][kb], sacc[m][n], 0, 0, 0);
    }
    __builtin_amdgcn_s_setprio(0);

    // optional mask (exp2 domain)
    if (use_mask) {
      #pragma unroll
      for (int m = 0; m < 2; m++) {
        int qg = q0 + m * 16 + lq;
        const float* mrow = mask + ((size_t)b * SEQ + qg) * SEQ + kv0;
        #pragma unroll
        for (int n = 0; n < 4; n++)
          #pragma unroll
          for (int j = 0; j < 4; j++)
            sacc[m][n][j] += mrow[n * 16 + g * 4 + j] * 1.44269504f;
      }
    }

    // row max for this lane's q: in-lane tree + 2 shfl (over g-groups)
    float pm[2];
    #pragma unroll
    for (int m = 0; m < 2; m++) {
      float a0 = fmaxf(fmaxf(sacc[m][0][0], sacc[m][0][1]), fmaxf(sacc[m][0][2], sacc[m][0][3]));
      float a1 = fmaxf(fmaxf(sacc[m][1][0], sacc[m][1][1]), fmaxf(sacc[m][1][2], sacc[m][1][3]));
      float a2 = fmaxf(fmaxf(sacc[m][2][0], sacc[m][2][1]), fmaxf(sacc[m][2][2], sacc[m][2][3]));
      float a3 = fmaxf(fmaxf(sacc[m][3][0], sacc[m][3][1]), fmaxf(sacc[m][3][2], sacc[m][3][3]));
      float v = fmaxf(fmaxf(a0, a1), fmaxf(a2, a3));
      v = fmaxf(v, __shfl_xor(v, 16, 64));
      v = fmaxf(v, __shfl_xor(v, 32, 64));
      pm[m] = v;
    }

    // defer-max: rescale only when some row's max grew (P stays <= 1)
    int nogrow = (pm[0] <= mrun[0]) && (pm[1] <= mrun[1]);
    if (!__all(nogrow)) {
      #pragma unroll
      for (int m = 0; m < 2; m++) {
        float mn = fmaxf(mrun[m], pm[m]);
        float sf = exp2_fast(mrun[m] - mn);
        mrun[m] = mn;
        lrun[m] *= sf;
        // oacc rows are q = m*16 + g*4 + j; fetch that q's sf from lane g*4+j
        float sfj[4];
        #pragma unroll
        for (int j = 0; j < 4; j++) sfj[j] = __shfl(sf, (g << 2) + j, 64);
        #pragma unroll
        for (int n = 0; n < 4; n++)
          #pragma unroll
          for (int j = 0; j < 4; j++)
            oacc[m][n][j] *= sfj[j];
      }
    }

    // P = exp2(S - m): one 8B bf16x4 write per (m,n); row-sum via tree
    #pragma unroll
    for (int m = 0; m < 2; m++) {
      float rsn[4];
      #pragma unroll
      for (int n = 0; n < 4; n++) {
        float e0 = exp2_fast(sacc[m][n][0] - mrun[m]);
        float e1 = exp2_fast(sacc[m][n][1] - mrun[m]);
        float e2 = exp2_fast(sacc[m][n][2] - mrun[m]);
        float e3 = exp2_fast(sacc[m][n][3] - mrun[m]);
        rsn[n] = (e0 + e1) + (e2 + e3);
        bf16x4 p = {(bf16)e0, (bf16)e1, (bf16)e2, (bf16)e3};
        *(bf16x4*)(Pw + pWOff[m][n]) = p;
      }
      float rs = (rsn[0] + rsn[1]) + (rsn[2] + rsn[3]);
      rs += __shfl_xor(rs, 16, 64);
      rs += __shfl_xor(rs, 32, 64);
      lrun[m] += rs;
    }

    // wave-private P: drain LDS writes before fragment reads
    asm volatile("s_waitcnt lgkmcnt(0)" ::: "memory");
    __builtin_amdgcn_sched_barrier(0);

    // O += P @ V   (A = P rows q, B = V^T rows d)
    __builtin_amdgcn_s_setprio(1);
    #pragma unroll
    for (int kb = 0; kb < 2; kb++) {
      bf16x8 pf[2], vf[4];
      #pragma unroll
      for (int m = 0; m < 2; m++)
        pf[m] = *(const bf16x8*)(Pw + pROff[m][kb]);
      #pragma unroll
      for (int n = 0; n < 4; n++)
        vf[n] = *(const bf16x8*)(Vlds + kvOff[kb][n]);
      #pragma unroll
      for (int m = 0; m < 2; m++)
        #pragma unroll
        for (int n = 0; n < 4; n++)
          oacc[m][n] = __builtin_amdgcn_mfma_f32_16x16x32_bf16(pf[m], vf[n], oacc[m][n], 0, 0, 0);
    }
    __builtin_amdgcn_s_setprio(0);

    __syncthreads();   // implicit vmcnt(0): prefetch landed; all reads of cur done
    cur ^= 1;
  }

  // normalize + write vals; oacc rows q = m*16+g*4+j -> lrun lives on lane g*4+j
  #pragma unroll
  for (int m = 0; m < 2; m++) {
    float inv[4];
    #pragma unroll
    for (int j = 0; j < 4; j++)
      inv[j] = 1.f / __shfl(lrun[m], (g << 2) + j, 64);
    #pragma unroll
    for (int n = 0; n < 4; n++) {
      int cg = h * HD + n * 16 + lq;
      #pragma unroll
      for (int j = 0; j < 4; j++) {
        int rg = b * SEQ + q0 + m * 16 + g * 4 + j;
        vals[(size_t)rg * D_MODEL + cg] = (bf16)(oacc[m][n][j] * inv[j]);
      }
    }
  }
}

extern "C" void kernel_launch(void* const* d_in, const int* in_sizes, int n_in,
                              void* d_out, int out_size, void* d_ws, size_t ws_size,
                              hipStream_t stream) {
  const float* x    = (const float*)d_in[0];
  const float* y    = (const float*)d_in[1];
  const float* mask = (const float*)d_in[2];
  const float* Wkv  = (const float*)d_in[3];
  const float* bkv  = (const float*)d_in[4];
  const float* Wq   = (const float*)d_in[5];
  const float* bq   = (const float*)d_in[6];
  const float* Wo   = (const float*)d_in[7];
  const float* bo   = (const float*)d_in[8];
  float* out = (float*)d_out;

  char* ws = (char*)d_ws;
  bf16* xb   = (bf16*)(ws);                      // 8 MB
  bf16* yb   = (bf16*)(ws + (8ull << 20));       // 8 MB
  bf16* Wkvt = (bf16*)(ws + (16ull << 20));      // 4 MB
  bf16* Wqt  = (bf16*)(ws + (20ull << 20));      // 2 MB
  bf16* Wot  = (bf16*)(ws + (22ull << 20));      // 2 MB
  bf16* KVb  = (bf16*)(ws + (24ull << 20));      // 16 MB (V half unused)
  bf16* Qbuf = (bf16*)(ws + (40ull << 20));      // 8 MB
  bf16* Vt   = (bf16*)(ws + (48ull << 20));      // 8 MB
  bf16* vals = (bf16*)(ws + (56ull << 20));      // 8 MB
  int*  flag = (int*)(ws + (64ull << 20));       // 4 B

  const float QSCL = 0.125f * 1.44269504f;   // 1/sqrt(64) * log2(e)

  hipMemsetAsync(flag, 0, 4, stream);
  mask_scan<<<2048, 256, 0, stream>>>(mask, BATCH * SEQ * SEQ / 4, flag);
  cvt_bf16<<<2048, 256, 0, stream>>>(x, xb, BS * D_MODEL / 8);
  cvt_bf16<<<2048, 256, 0, stream>>>(y, yb, BS * D_MODEL / 8);
  transpose_cvt<<<dim3(16, 32), 256, 0, stream>>>(Wkv, Wkvt, 1024, 2048);
  transpose_cvt<<<dim3(16, 16), 256, 0, stream>>>(Wq, Wqt, 1024, 1024);
  transpose_cvt<<<dim3(16, 16), 256, 0, stream>>>(Wo, Wot, 1024, 1024);
  // KV GEMM: K half -> KVb, V half -> Vt (transposed in epilogue)
  gemm_bt<bf16, 1><<<dim3(32, 16), 256, 0, stream>>>(xb, Wkvt, bkv, KVb, Vt, 4096, 2048, 1024, 1.0f);
  // Q GEMM: pre-scale into exp2 domain
  gemm_bt<bf16, 0><<<dim3(32, 8), 256, 0, stream>>>(yb, Wqt, bq, Qbuf, nullptr, 4096, 1024, 1024, QSCL);
  attn_kernel<<<512, 256, 0, stream>>>(Qbuf, KVb, Vt, mask, flag, vals);
  gemm_bt<float, 0><<<dim3(32, 8), 256, 0, stream>>>(vals, Wot, bo, out, nullptr, 4096, 1024, 1024, 1.0f);
}

// Round 11
// 160.278 us; speedup vs baseline: 1.1734x; 1.0654x over previous
//
#include <hip/hip_runtime.h>
#include <hip/hip_bf16.h>

#define D_MODEL 1024
#define NHEADS 16
#define HD 64
#define BATCH 2
#define SEQ 2048
#define BS (BATCH*SEQ)   // 4096

typedef __bf16 bf16;
typedef bf16 bf16x4 __attribute__((ext_vector_type(4)));
typedef bf16 bf16x8 __attribute__((ext_vector_type(8)));
typedef float f32x4 __attribute__((ext_vector_type(4)));

#define AS1 __attribute__((address_space(1)))
#define AS3 __attribute__((address_space(3)))

__device__ __forceinline__ void gload_lds16(const void* g, void* l) {
  __builtin_amdgcn_global_load_lds((AS1 const unsigned int*)g, (AS3 unsigned int*)l, 16, 0, 0);
}

// 2^x as a single v_exp_f32 (+ s_nop for the trans-op read hazard).
// NON-volatile: pure value -> compiler may schedule/interleave freely.
__device__ __forceinline__ float exp2_fast(float x) {
  float r;
  asm("v_exp_f32 %0, %1\n\ts_nop 1" : "=v"(r) : "v"(x));
  return r;
}

// ---------------- elementwise f32 -> bf16 ----------------
__global__ void cvt_bf16(const float* __restrict__ in, bf16* __restrict__ out, int n8) {
  int i = blockIdx.x * blockDim.x + threadIdx.x;
  int stride = gridDim.x * blockDim.x;
  for (; i < n8; i += stride) {
    const float4* p = (const float4*)(in + (size_t)i * 8);
    float4 a = p[0], b = p[1];
    bf16x8 o;
    o[0]=(bf16)a.x; o[1]=(bf16)a.y; o[2]=(bf16)a.z; o[3]=(bf16)a.w;
    o[4]=(bf16)b.x; o[5]=(bf16)b.y; o[6]=(bf16)b.z; o[7]=(bf16)b.w;
    *(bf16x8*)(out + (size_t)i * 8) = o;
  }
}

// ---------------- transpose+convert: in f32 [R][C] -> out bf16 [C][R] ----------------
__global__ void transpose_cvt(const float* __restrict__ in, bf16* __restrict__ out, int R, int C) {
  __shared__ bf16 tile[64][72];
  const int t = threadIdx.x;
  const int r0 = blockIdx.x * 64;
  const int c0 = blockIdx.y * 64;
  {
    int r = t >> 2, cc = (t & 3) * 16;
    const float* src = in + (size_t)(r0 + r) * C + c0 + cc;
    #pragma unroll
    for (int j = 0; j < 16; j += 4) {
      float4 v = *(const float4*)(src + j);
      tile[r][cc + j + 0] = (bf16)v.x;
      tile[r][cc + j + 1] = (bf16)v.y;
      tile[r][cc + j + 2] = (bf16)v.z;
      tile[r][cc + j + 3] = (bf16)v.w;
    }
  }
  __syncthreads();
  {
    int c = t >> 2, rr = (t & 3) * 16;
    bf16* dst = out + (size_t)(c0 + c) * R + r0 + rr;
    bf16x8 o0, o1;
    #pragma unroll
    for (int j = 0; j < 8; j++) { o0[j] = tile[rr + j][c]; o1[j] = tile[rr + 8 + j][c]; }
    *(bf16x8*)dst = o0;
    *(bf16x8*)(dst + 8) = o1;
  }
}

// ---------------- mask zero-scan ----------------
__global__ void mask_scan(const float* __restrict__ mask, int n4, int* __restrict__ flag) {
  int i = blockIdx.x * blockDim.x + threadIdx.x;
  int stride = gridDim.x * blockDim.x;
  int any = 0;
  for (; i < n4; i += stride) {
    float4 v = *(const float4*)(mask + (size_t)i * 4);
    if (v.x != 0.f || v.y != 0.f || v.z != 0.f || v.w != 0.f) any = 1;
  }
  if (__ballot(any) && (threadIdx.x & 63) == 0) atomicOr(flag, 1);
}

// ---------------- GEMM: C[M][N] = (A[M][K] @ Bt[N][K]^T + bias) * scale ------
// MODE 0: plain C write.
// MODE 1 (KV GEMM, N=2048): wc==0 waves (K half of each head) write C;
//   wc==1 waves (V half) write acc TRANSPOSED to Vt[B][H][HD][SEQ] and skip C.
template <typename OutT, int MODE>
__global__ __launch_bounds__(256)
void gemm_bt(const bf16* __restrict__ A, const bf16* __restrict__ Bt,
             const float* __restrict__ bias, OutT* __restrict__ C,
             bf16* __restrict__ Vt, int M, int N, int K, float scale) {
  __shared__ char lds[32768];
  char* Alds = lds;
  char* Blds = lds + 16384;
  const int t = threadIdx.x;
  const int lane = t & 63;
  const int wid = t >> 6;
  const int m0 = blockIdx.x * 128;
  const int n0 = blockIdx.y * 128;
  const int wr = wid >> 1, wc = wid & 1;

  f32x4 acc[4][4] = {};

  int rowL[4], colL[4];
  #pragma unroll
  for (int i = 0; i < 4; i++) {
    int L = t * 16 + i * 4096;
    int r = L >> 7;
    rowL[i] = r;
    colL[i] = (L & 127) ^ ((r & 7) << 4);
  }
  const char* Ab = (const char*)A;
  const char* Bb = (const char*)Bt;
  const size_t rs = (size_t)K * 2;

  for (int k0 = 0; k0 < K; k0 += 64) {
    #pragma unroll
    for (int i = 0; i < 4; i++) {
      gload_lds16(Ab + (size_t)(m0 + rowL[i]) * rs + (size_t)k0 * 2 + colL[i],
                  Alds + i * 4096 + t * 16);
      gload_lds16(Bb + (size_t)(n0 + rowL[i]) * rs + (size_t)k0 * 2 + colL[i],
                  Blds + i * 4096 + t * 16);
    }
    __syncthreads();
    #pragma unroll
    for (int kb = 0; kb < 2; kb++) {
      bf16x8 af[4], bfr[4];
      #pragma unroll
      for (int m = 0; m < 4; m++) {
        int r = wr * 64 + m * 16 + (lane & 15);
        int cb = (kb * 64 + ((lane >> 4) << 4)) ^ ((r & 7) << 4);
        af[m] = *(const bf16x8*)(Alds + r * 128 + cb);
      }
      #pragma unroll
      for (int n = 0; n < 4; n++) {
        int r = wc * 64 + n * 16 + (lane & 15);
        int cb = (kb * 64 + ((lane >> 4) << 4)) ^ ((r & 7) << 4);
        bfr[n] = *(const bf16x8*)(Blds + r * 128 + cb);
      }
      #pragma unroll
      for (int m = 0; m < 4; m++)
        #pragma unroll
        for (int n = 0; n < 4; n++)
          acc[m][n] = __builtin_amdgcn_mfma_f32_16x16x32_bf16(af[m], bfr[n], acc[m][n], 0, 0, 0);
    }
    __syncthreads();
  }

  if (MODE == 1 && wc == 1) {
    // V half: columns cg = n0+64+n*16+lq  ->  head h = n0>>7, d = n*16+lq.
    // Rows rb+j (j=0..3 consecutive) -> contiguous bf16x4 at Vt[d][s..s+3].
    const int h = n0 >> 7;
    const int bb = m0 >> 11;          // 128-row tiles never straddle batches
    #pragma unroll
    for (int n = 0; n < 4; n++) {
      const int d = n * 16 + (lane & 15);
      const int cg = n0 + 64 + d;
      const float bv = bias[cg];
      bf16* vrow = Vt + ((size_t)((bb * NHEADS + h) * HD + d)) * SEQ;
      #pragma unroll
      for (int m = 0; m < 4; m++) {
        const int rb = m0 + wr * 64 + m * 16 + ((lane >> 4) << 2);
        const int s = rb & (SEQ - 1);
        bf16x4 v;
        #pragma unroll
        for (int j = 0; j < 4; j++) v[j] = (bf16)((acc[m][n][j] + bv) * scale);
        *(bf16x4*)(vrow + s) = v;
      }
    }
  } else {
    #pragma unroll
    for (int m = 0; m < 4; m++) {
      const int rb = m0 + wr * 64 + m * 16 + ((lane >> 4) << 2);
      #pragma unroll
      for (int n = 0; n < 4; n++) {
        const int cg = n0 + wc * 64 + n * 16 + (lane & 15);
        const float bv = bias[cg];
        #pragma unroll
        for (int j = 0; j < 4; j++) {
          C[(size_t)(rb + j) * N + cg] = (OutT)((acc[m][n][j] + bv) * scale);
        }
      }
    }
  }
}

// ---------------- flash attention (swapped QK^T, dbuf, 32q/wave, T13) --------
// 4 waves x 32 q-rows = 128 q/block; grid = B*H*(SEQ/128) = 512 blocks.
// Q pre-scaled by 0.125*log2(e) -> QK^T lands in exp2 domain.
// mfma(K,Q): each lane holds P of ONE q row (q=lane&15).
// Defer-max with THR=8 (exp2 domain): P bounded by 2^8 -- relative bf16
// precision unchanged (numerator and denominator share the scale), rescale
// body runs ~2/32 iterations instead of ~30/32.
// lrun kept as PER-LANE PARTIAL (16 kv of the row); cross-g reduce once in
// the epilogue (valid: all g-copies of a row share identical mrun/sf).
__global__ __launch_bounds__(256)
void attn_kernel(const bf16* __restrict__ Qb, const bf16* __restrict__ KV,
                 const bf16* __restrict__ Vt, const float* __restrict__ mask,
                 const int* __restrict__ flag, bf16* __restrict__ vals) {
  __shared__ char lds[49152];
  // buf c: K at c*16384, V at c*16384+8192; P per wave at 32768 + wid*4096
  const int t = threadIdx.x;
  const int lane = t & 63;
  const int wid = t >> 6;
  const int g = lane >> 4;          // 16-lane group 0..3
  const int lq = lane & 15;         // this lane's q within 16
  char* Pw = lds + 32768 + wid * 4096;   // [32 q][128B], XOR-swizzled rows

  // XCD-bijective swizzle: 512 blocks, 8 XCDs, 64 consecutive logical wgs
  // per XCD (same b, 4 heads -> 2MB K+V fits 4MB L2).
  int wg = ((blockIdx.x & 7) << 6) | (blockIdx.x >> 3);
  const int qt = wg & 15;
  const int h = (wg >> 4) & 15;
  const int b = wg >> 8;
  const int q0 = qt * 128 + wid * 32;
  const bool use_mask = (*flag) != 0;

  // Q fragments (B-operand: rows = q)
  bf16x8 qf[2][2];
  #pragma unroll
  for (int m = 0; m < 2; m++)
    #pragma unroll
    for (int kb = 0; kb < 2; kb++) {
      int r = q0 + m * 16 + lq;
      qf[m][kb] = *(const bf16x8*)(Qb + (size_t)(b * SEQ + r) * D_MODEL + h * HD + kb * 32 + g * 8);
    }

  f32x4 oacc[2][4] = {};
  float mrun[2], lrun[2];
  mrun[0] = mrun[1] = -1e30f;
  lrun[0] = lrun[1] = 0.f;

  // hoisted LDS byte offsets (loop-invariant)
  int kvOff[2][4];   // K and V fragment offsets (same formula)
  #pragma unroll
  for (int kb = 0; kb < 2; kb++)
    #pragma unroll
    for (int n = 0; n < 4; n++) {
      int r = n * 16 + lq;
      kvOff[kb][n] = r * 128 + ((kb * 64 + (g << 4)) ^ ((r & 7) << 4));
    }
  int pROff[2][2];   // P read offsets per (m, kb)
  #pragma unroll
  for (int m = 0; m < 2; m++)
    #pragma unroll
    for (int kb = 0; kb < 2; kb++) {
      int r = m * 16 + lq;
      pROff[m][kb] = r * 128 + ((kb * 64 + (g << 4)) ^ ((r & 7) << 4));
    }
  int pWOff[2][4];   // P write offsets per (m, n)
  #pragma unroll
  for (int m = 0; m < 2; m++) {
    int r = m * 16 + lq;
    int swz = (r & 7) << 4;
    #pragma unroll
    for (int n = 0; n < 4; n++)
      pWOff[m][n] = r * 128 + ((n * 32 + g * 8) ^ swz);
  }

  int rowL[2], colL[2];
  #pragma unroll
  for (int i = 0; i < 2; i++) {
    int L = t * 16 + i * 4096;
    int r = L >> 7;
    rowL[i] = r;
    colL[i] = (L & 127) ^ ((r & 7) << 4);
  }
  const char* KVb = (const char*)KV;
  const char* Vtb = (const char*)Vt;

  // stage K/V tile kt into buffer c
  auto stage = [&](int kt, int c) {
    const int kv0 = kt * 64;
    char* Kb = lds + c * 16384;
    char* Vb = Kb + 8192;
    #pragma unroll
    for (int i = 0; i < 2; i++) {
      gload_lds16(KVb + (size_t)(b * SEQ + kv0 + rowL[i]) * (2 * D_MODEL * 2) + h * 256 + colL[i],
                  Kb + i * 4096 + t * 16);
      gload_lds16(Vtb + (size_t)((b * NHEADS + h) * HD + rowL[i]) * (SEQ * 2) + kv0 * 2 + colL[i],
                  Vb + i * 4096 + t * 16);
    }
  };

  stage(0, 0);
  __syncthreads();
  int cur = 0;

  const int NT = SEQ / 64;
  for (int kt = 0; kt < NT; kt++) {
    if (kt + 1 < NT) stage(kt + 1, cur ^ 1);   // prefetch overlaps compute
    char* Klds = lds + cur * 16384;
    char* Vlds = Klds + 8192;
    const int kv0 = kt * 64;

    // S^T = K Q^T (already exp2-domain): sacc[m][n] row = kv, col = q (lq)
    f32x4 sacc[2][4] = {};
    __builtin_amdgcn_s_setprio(1);
    #pragma unroll
    for (int kb = 0; kb < 2; kb++) {
      bf16x8 kf[4];
      #pragma unroll
      for (int n = 0; n < 4; n++)
        kf[n] = *(const bf16x8*)(Klds + kvOff[kb][n]);
      #pragma unroll
      for (int m = 0; m < 2; m++)
        #pragma unroll
        for (int n = 0; n < 4; n++)
          sacc[m][n] = __builtin_amdgcn_mfma_f32_16x16x32_bf16(kf[n], qf[m][kb], sacc[m][n], 0, 0, 0);
    }
    __builtin_amdgcn_s_setprio(0);

    // optional mask (exp2 domain)
    if (use_mask) {
      #pragma unroll
      for (int m = 0; m < 2; m++) {
        int qg = q0 + m * 16 + lq;
        const float* mrow = mask + ((size_t)b * SEQ + qg) * SEQ + kv0;
        #pragma unroll
        for (int n = 0; n < 4; n++)
          #pragma unroll
          for (int j = 0; j < 4; j++)
            sacc[m][n][j] += mrow[n * 16 + g * 4 + j] * 1.44269504f;
      }
    }

    // row max for this lane's q: in-lane tree + 2 shfl (over g-groups)
    float pm[2];
    #pragma unroll
    for (int m = 0; m < 2; m++) {
      float a0 = fmaxf(fmaxf(sacc[m][0][0], sacc[m][0][1]), fmaxf(sacc[m][0][2], sacc[m][0][3]));
      float a1 = fmaxf(fmaxf(sacc[m][1][0], sacc[m][1][1]), fmaxf(sacc[m][1][2], sacc[m][1][3]));
      float a2 = fmaxf(fmaxf(sacc[m][2][0], sacc[m][2][1]), fmaxf(sacc[m][2][2], sacc[m][2][3]));
      float a3 = fmaxf(fmaxf(sacc[m][3][0], sacc[m][3][1]), fmaxf(sacc[m][3][2], sacc[m][3][3]));
      float v = fmaxf(fmaxf(a0, a1), fmaxf(a2, a3));
      v = fmaxf(v, __shfl_xor(v, 16, 64));
      v = fmaxf(v, __shfl_xor(v, 32, 64));
      pm[m] = v;
    }

    // T13 defer-max THR=8: rescale only when a row's max grew past mrun+8.
    // P stays <= 2^8; relative bf16 precision of P and lrun is unaffected.
    int nogrow = (pm[0] <= mrun[0] + 8.f) && (pm[1] <= mrun[1] + 8.f);
    if (!__all(nogrow)) {
      #pragma unroll
      for (int m = 0; m < 2; m++) {
        float mn = fmaxf(mrun[m], pm[m]);
        float sf = exp2_fast(mrun[m] - mn);
        mrun[m] = mn;
        lrun[m] *= sf;
        // oacc rows are q = m*16 + g*4 + j; fetch that q's sf from lane g*4+j
        float sfj[4];
        #pragma unroll
        for (int j = 0; j < 4; j++) sfj[j] = __shfl(sf, (g << 2) + j, 64);
        #pragma unroll
        for (int n = 0; n < 4; n++)
          #pragma unroll
          for (int j = 0; j < 4; j++)
            oacc[m][n][j] *= sfj[j];
      }
    }

    // P = exp2(S - m): one 8B bf16x4 write per (m,n); lrun accumulates the
    // PER-LANE partial (this lane's 16 kv of the row) -- no per-iter reduce.
    #pragma unroll
    for (int m = 0; m < 2; m++) {
      float rsn[4];
      #pragma unroll
      for (int n = 0; n < 4; n++) {
        float e0 = exp2_fast(sacc[m][n][0] - mrun[m]);
        float e1 = exp2_fast(sacc[m][n][1] - mrun[m]);
        float e2 = exp2_fast(sacc[m][n][2] - mrun[m]);
        float e3 = exp2_fast(sacc[m][n][3] - mrun[m]);
        rsn[n] = (e0 + e1) + (e2 + e3);
        bf16x4 p = {(bf16)e0, (bf16)e1, (bf16)e2, (bf16)e3};
        *(bf16x4*)(Pw + pWOff[m][n]) = p;
      }
      lrun[m] += (rsn[0] + rsn[1]) + (rsn[2] + rsn[3]);
    }

    // wave-private P: drain LDS writes before fragment reads
    asm volatile("s_waitcnt lgkmcnt(0)" ::: "memory");
    __builtin_amdgcn_sched_barrier(0);

    // O += P @ V   (A = P rows q, B = V^T rows d)
    __builtin_amdgcn_s_setprio(1);
    #pragma unroll
    for (int kb = 0; kb < 2; kb++) {
      bf16x8 pf[2], vf[4];
      #pragma unroll
      for (int m = 0; m < 2; m++)
        pf[m] = *(const bf16x8*)(Pw + pROff[m][kb]);
      #pragma unroll
      for (int n = 0; n < 4; n++)
        vf[n] = *(const bf16x8*)(Vlds + kvOff[kb][n]);
      #pragma unroll
      for (int m = 0; m < 2; m++)
        #pragma unroll
        for (int n = 0; n < 4; n++)
          oacc[m][n] = __builtin_amdgcn_mfma_f32_16x16x32_bf16(pf[m], vf[n], oacc[m][n], 0, 0, 0);
    }
    __builtin_amdgcn_s_setprio(0);

    __syncthreads();   // implicit vmcnt(0): prefetch landed; all reads of cur done
    cur ^= 1;
  }

  // reduce lrun partials across g-groups (identical mrun/sf per row-copy)
  #pragma unroll
  for (int m = 0; m < 2; m++) {
    lrun[m] += __shfl_xor(lrun[m], 16, 64);
    lrun[m] += __shfl_xor(lrun[m], 32, 64);
  }

  // normalize + write vals; oacc rows q = m*16+g*4+j -> lrun lives on lane g*4+j
  #pragma unroll
  for (int m = 0; m < 2; m++) {
    float inv[4];
    #pragma unroll
    for (int j = 0; j < 4; j++)
      inv[j] = 1.f / __shfl(lrun[m], (g << 2) + j, 64);
    #pragma unroll
    for (int n = 0; n < 4; n++) {
      int cg = h * HD + n * 16 + lq;
      #pragma unroll
      for (int j = 0; j < 4; j++) {
        int rg = b * SEQ + q0 + m * 16 + g * 4 + j;
        vals[(size_t)rg * D_MODEL + cg] = (bf16)(oacc[m][n][j] * inv[j]);
      }
    }
  }
}

extern "C" void kernel_launch(void* const* d_in, const int* in_sizes, int n_in,
                              void* d_out, int out_size, void* d_ws, size_t ws_size,
                              hipStream_t stream) {
  const float* x    = (const float*)d_in[0];
  const float* y    = (const float*)d_in[1];
  const float* mask = (const float*)d_in[2];
  const float* Wkv  = (const float*)d_in[3];
  const float* bkv  = (const float*)d_in[4];
  const float* Wq   = (const float*)d_in[5];
  const float* bq   = (const float*)d_in[6];
  const float* Wo   = (const float*)d_in[7];
  const float* bo   = (const float*)d_in[8];
  float* out = (float*)d_out;

  char* ws = (char*)d_ws;
  bf16* xb   = (bf16*)(ws);                      // 8 MB
  bf16* yb   = (bf16*)(ws + (8ull << 20));       // 8 MB
  bf16* Wkvt = (bf16*)(ws + (16ull << 20));      // 4 MB
  bf16* Wqt  = (bf16*)(ws + (20ull << 20));      // 2 MB
  bf16* Wot  = (bf16*)(ws + (22ull << 20));      // 2 MB
  bf16* KVb  = (bf16*)(ws + (24ull << 20));      // 16 MB (V half unused)
  bf16* Qbuf = (bf16*)(ws + (40ull << 20));      // 8 MB
  bf16* Vt   = (bf16*)(ws + (48ull << 20));      // 8 MB
  bf16* vals = (bf16*)(ws + (56ull << 20));      // 8 MB
  int*  flag = (int*)(ws + (64ull << 20));       // 4 B

  const float QSCL = 0.125f * 1.44269504f;   // 1/sqrt(64) * log2(e)

  hipMemsetAsync(flag, 0, 4, stream);
  mask_scan<<<2048, 256, 0, stream>>>(mask, BATCH * SEQ * SEQ / 4, flag);
  cvt_bf16<<<2048, 256, 0, stream>>>(x, xb, BS * D_MODEL / 8);
  cvt_bf16<<<2048, 256, 0, stream>>>(y, yb, BS * D_MODEL / 8);
  transpose_cvt<<<dim3(16, 32), 256, 0, stream>>>(Wkv, Wkvt, 1024, 2048);
  transpose_cvt<<<dim3(16, 16), 256, 0, stream>>>(Wq, Wqt, 1024, 1024);
  transpose_cvt<<<dim3(16, 16), 256, 0, stream>>>(Wo, Wot, 1024, 1024);
  // KV GEMM: K half -> KVb, V half -> Vt (transposed in epilogue)
  gemm_bt<bf16, 1><<<dim3(32, 16), 256, 0, stream>>>(xb, Wkvt, bkv, KVb, Vt, 4096, 2048, 1024, 1.0f);
  // Q GEMM: pre-scale into exp2 domain
  gemm_bt<bf16, 0><<<dim3(32, 8), 256, 0, stream>>>(yb, Wqt, bq, Qbuf, nullptr, 4096, 1024, 1024, QSCL);
  attn_kernel<<<512, 256, 0, stream>>>(Qbuf, KVb, Vt, mask, flag, vals);
  gemm_bt<float, 0><<<dim3(32, 8), 256, 0, stream>>>(vals, Wot, bo, out, nullptr, 4096, 1024, 1024, 1.0f);
}